// Round 1
// baseline (165.190 us; speedup 1.0000x reference)
//
#include <hip/hip_runtime.h>
#include <stdint.h>

typedef unsigned short u16;
typedef __attribute__((ext_vector_type(8))) short short8;
typedef __attribute__((ext_vector_type(4))) float floatx4;

#define NB 32
#define NC 256
#define NH 32
#define NW 32
#define NO 256
#define NPIX (NH*NW)     // 1024
#define KPIX 9
#define NG 9             // subarrays (groups)
#define RUN 32           // padded run length (per kernel-tap within group)
#define GK (NG*RUN)      // 288 k-slots per group
#define KTOT (NG*GK)     // 2592 k-slots
#define PADH 34
#define PADSP (PADH*PADH)       // 1156
#define QA_BSTRIDE (PADSP*NC)   // 295936 elems per batch

#define AS1 __attribute__((address_space(1)))
#define AS3 __attribute__((address_space(3)))

// ---------------- fused: per-block absmax slots + zero qa halo borders ----------------
// blocks [0,1024): x-max -> pmax[bid] ; [1024,1088): w-max ; [1088,1376): border zero
__global__ void fused_pre(const float4* __restrict__ x4, int nx4,
                          const float4* __restrict__ w4, int nw4,
                          float* __restrict__ pmax, u16* __restrict__ qa) {
  int bid = blockIdx.x;
  if (bid >= 1088) {
    int zb = bid - 1088;              // 9 blocks per batch
    int b = zb / 9;
    int rem = (zb % 9) * 256 + threadIdx.x;   // need <2112 (132 px * 16 ch-groups)
    if (rem >= 2112) return;
    int pb = rem >> 4, c16 = rem & 15;
    int y, x;
    if (pb < 68) { y = (pb >= 34) ? 33 : 0; x = pb % 34; }
    else { int q = pb - 68; y = 1 + (q >> 1); x = (q & 1) ? 33 : 0; }
    uint4 z; z.x = z.y = z.z = z.w = 0u;
    *(uint4*)(qa + ((size_t)(b * PADH + y) * PADH + x) * NC + c16 * 16) = z;
    return;
  }
  const float4* p; int n4; int nb, b0;
  if (bid < 1024) { p = x4; n4 = nx4; nb = 1024; b0 = bid; }
  else            { p = w4; n4 = nw4; nb = 64;   b0 = bid - 1024; }
  float m = 0.f;
  for (int i = b0 * blockDim.x + threadIdx.x; i < n4; i += nb * blockDim.x) {
    float4 v = p[i];
    m = fmaxf(m, fmaxf(fmaxf(fabsf(v.x), fabsf(v.y)), fmaxf(fabsf(v.z), fabsf(v.w))));
  }
#pragma unroll
  for (int off = 32; off > 0; off >>= 1)
    m = fmaxf(m, __shfl_down(m, off, 64));
  __shared__ float sm[4];
  int lane = threadIdx.x & 63, wv = threadIdx.x >> 6;
  if (lane == 0) sm[wv] = m;
  __syncthreads();
  if (threadIdx.x == 0)
    pmax[bid] = fmaxf(fmaxf(sm[0], sm[1]), fmaxf(sm[2], sm[3]));
}

// helper: reduce the 1024 x-slots and 64 w-slots
__device__ inline void reduce_pmax(const float* pmax, int tid, int nthreads,
                                   float* sred, float& mx_out, float& mw_out) {
  const float4* pf4 = (const float4*)pmax;
  float mx = 0.f, mw = 0.f;
  for (int t = tid; t < 256; t += nthreads) {
    float4 v = pf4[t];
    mx = fmaxf(mx, fmaxf(fmaxf(v.x, v.y), fmaxf(v.z, v.w)));
  }
  if (tid < 16) {
    float4 v = pf4[256 + tid];
    mw = fmaxf(fmaxf(v.x, v.y), fmaxf(v.z, v.w));
  }
#pragma unroll
  for (int off = 32; off > 0; off >>= 1) {
    mx = fmaxf(mx, __shfl_down(mx, off, 64));
    mw = fmaxf(mw, __shfl_down(mw, off, 64));
  }
  int lane = tid & 63, wv = tid >> 6, nw = nthreads >> 6;
  if (lane == 0) { sred[wv] = mx; sred[8 + wv] = mw; }
  __syncthreads();
  mx = sred[0]; mw = sred[8];
  for (int i = 1; i < nw; i++) { mx = fmaxf(mx, sred[i]); mw = fmaxf(mw, sred[8 + i]); }
  mx_out = mx; mw_out = mw;
}

// ---------------- fused quantization: acts (blocks <1024, vectorized) + weights ----------------
// act: one block per (b,y): 256c x 32x tile. float4 loads, LDS transpose, uint4 stores.
// f64 math EXACTLY as all passing rounds: rint((double)v * (255/s)).
__global__ void fused_quant(const float* __restrict__ x, const float* __restrict__ w,
                            const float* __restrict__ pmax,
                            u16* __restrict__ qa, u16* __restrict__ wq,
                            float* __restrict__ lossp) {
  __shared__ float sred[16];
  float mx, mw;
  reduce_pmax(pmax, threadIdx.x, 256, sred, mx, mw);
  int bid = blockIdx.x, tid = threadIdx.x;
  if (bid < 1024) {
    __shared__ u16 ts[32][264];        // [x][c], row stride 264 (16B-aligned rows)
    double s = (double)mx + 1e-12;
    double inv = 255.0 / s;
    int b = bid >> 5, y = bid & 31;
    const float4* x4 = (const float4*)x;
    int xc = tid & 7, crow = tid >> 3;
#pragma unroll
    for (int it = 0; it < 8; it++) {
      int c = crow + 32 * it;
      float4 v = x4[((size_t)(b * NC + c) * NH + y) * 8 + xc];
      float q0 = (float)rint((double)v.x * inv);
      float q1 = (float)rint((double)v.y * inv);
      float q2 = (float)rint((double)v.z * inv);
      float q3 = (float)rint((double)v.w * inv);
      ts[xc * 4 + 0][c] = (u16)(__float_as_uint(q0) >> 16);
      ts[xc * 4 + 1][c] = (u16)(__float_as_uint(q1) >> 16);
      ts[xc * 4 + 2][c] = (u16)(__float_as_uint(q2) >> 16);
      ts[xc * 4 + 3][c] = (u16)(__float_as_uint(q3) >> 16);
    }
    __syncthreads();
    int xx = tid >> 3, qwl = tid & 7;
    u16* orow = qa + ((size_t)(b * PADH + y + 1) * PADH + (xx + 1)) * NC;
#pragma unroll
    for (int it = 0; it < 4; it++) {
      int qw = qwl + 8 * it;
      *(uint4*)(orow + qw * 8) = *(const uint4*)&ts[xx][qw * 8];
    }
    return;
  }
  // ---- weights: 2592 blocks cover NO*KTOT = 663552 slots exactly ----
  double s = (double)mw + 1e-12;
  double inv = 15.0 / s;
  int idx = (bid - 1024) * 256 + tid;
  if (idx == 0) *lossp = 0.0f;                  // a_loss output
  int o = idx / KTOT, kk = idx % KTOT;
  int g = kk / GK, rem = kk % GK;
  int r = rem / RUN, j = rem % RUN;
  int clo = (256 * g - r + 8) / 9;
  int chi = (256 * (g + 1) - r + 8) / 9; if (chi > NC) chi = NC;
  int cst = clo & ~3;
  int c = cst + j;
  float val = 0.f;
  if (c >= clo && c < chi) {
    float wv = w[((size_t)o * NC + c) * KPIX + r];
    val = (float)rint((double)wv * inv);
  }
  wq[idx] = (u16)(__float_as_uint(val) >> 16);
}

// ---------------- fused GEMM + per-group ADC ----------------
// 256x128 block tile, 512 threads (8 waves: 4M x 2N of 64x64), grid (128,2)=256 blocks
// = exactly 1/CU. Staged bytes 509.6 MB (vs prior 680): A duplicated only x2 (nblk),
// B duplicated x128 (mblk) but A-tile is now 2x taller. Double-buffered 96-K chunks
// (LDS 144 KB) with counted s_waitcnt vmcnt(9) + raw s_barrier (T3+T4): the
// global_load_lds queue is NEVER drained to 0 inside the loop, so staging streams
// continuously across barriers (prior version drained 27x/block via __syncthreads).
// 1/CU is safe *with* this pipeline (8-phase-template evidence); the earlier 1/CU
// failure (R8) was with full drains. T5 setprio wraps the MFMA cluster. Source-side
// bank swizzle identical to prior rounds (row-parity based; still conflict-free at
// 256 rows since wm, mi*16 are ==0 mod 4 after >>1). f64 ADC fold EXACTLY as before,
// placed right after load-issue so its ~450 VALU ops hide under in-flight staging.
__global__ __launch_bounds__(512, 2) void gemm_adc(const u16* __restrict__ qa,
                                                   const u16* __restrict__ wq,
                                                   const float* __restrict__ pmax,
                                                   float* __restrict__ out) {
  __shared__ u16 lA[2 * 3 * 256 * RUN];   // 96 KB: 2 bufs x 3 runs x 256 rows x 32
  __shared__ u16 lB[2 * 3 * 128 * RUN];   // 48 KB: 2 bufs x 3 runs x 128 rows x 32
  __shared__ float sred[16];
  const int tid = threadIdx.x;
  float mx, mw;
  reduce_pmax(pmax, tid, 512, sred, mx, mw);

  const int mblk = blockIdx.x, nblk = blockIdx.y;
  const int b = mblk >> 2;                // 4 pixel-tiles of 256 per batch
  const int p0 = (mblk & 3) * 256;        // pixel base (8 image rows of 32)
  const int n0 = nblk * 128;
  const int lane = tid & 63, wv = tid >> 6;
  const int wm = (wv & 3) * 64, wn = (wv >> 2) * 64;
  const int fm = lane & 15, fq = lane >> 4;
  const int swz = (fq + ((fm >> 1) & 3)) & 3;

  double sa = (double)mx + 1e-12;
  double sw = (double)mw + 1e-12;
  double Sstep = sa * sw * 0.999 / 459.0;   // I/step = intsum * Sstep

  // staging: A slab i (0..5): run = i>>1, row = (tid>>2) + 128*(i&1), j' = tid&3
  //          B slab i (0..2): run = i,    row = tid>>2,               j' = tid&3
  // LDS dest (u16) = buf + i*4096 + tid*8 (wave-uniform base + lane*16B, linear).
  // global k-word jsrc = (j' - ((row>>1)&3)) & 3 = ((tid&3) - ((tid>>3)&3)) & 3
  const int r0 = tid >> 2;
  const int jsrc = ((tid & 3) - ((tid >> 3) & 3)) & 3;
  const u16* AbH[2];
#pragma unroll
  for (int h = 0; h < 2; h++) {
    int p = p0 + r0 + 128 * h;
    AbH[h] = qa + (size_t)b * QA_BSTRIDE
             + (((p >> 5) + 1) * PADH + ((p & 31) + 1)) * NC + jsrc * 8;
  }
  const u16* Bb = wq + (size_t)(n0 + r0) * KTOT + jsrc * 8;

  floatx4 acc[4][4];
  float tot[4][4][4];
#pragma unroll
  for (int mi = 0; mi < 4; mi++)
#pragma unroll
    for (int ni = 0; ni < 4; ni++)
#pragma unroll
      for (int rr = 0; rr < 4; rr++) { acc[mi][ni][rr] = 0.f; tot[mi][ni][rr] = 0.f; }

  auto STAGE = [&](int gs, int rcs, int aB, int bB) {
    int offA[3], kb[3];
#pragma unroll
    for (int ri = 0; ri < 3; ri++) {
      int r = rcs * 3 + ri;
      int cst = ((256 * gs - r + 8) / 9) & ~3;
      offA[ri] = ((rcs - 1) * PADH + (ri - 1)) * NC + cst;  // (dy*34+dx)*256 + cst
      kb[ri] = gs * GK + r * RUN;
    }
#pragma unroll
    for (int i = 0; i < 6; i++)
      __builtin_amdgcn_global_load_lds(
          (const AS1 void*)(AbH[i & 1] + offA[i >> 1]),
          (AS3 void*)&lA[aB + i * 4096 + tid * 8], 16, 0, 0);
#pragma unroll
    for (int i = 0; i < 3; i++)
      __builtin_amdgcn_global_load_lds(
          (const AS1 void*)(Bb + kb[i]),
          (AS3 void*)&lB[bB + i * 4096 + tid * 8], 16, 0, 0);
  };

  auto FOLD = [&]() {
#pragma unroll
    for (int mi = 0; mi < 4; mi++)
#pragma unroll
      for (int ni = 0; ni < 4; ni++)
#pragma unroll
        for (int rr = 0; rr < 4; rr++) {
          double d = (double)acc[mi][ni][rr] * Sstep;
          float tf = (float)rint(d);
          tf = fminf(fmaxf(tf, -128.f), 127.f);
          tot[mi][ni][rr] += tf;
          acc[mi][ni][rr] = 0.f;
        }
  };

  // prologue: stage chunk 0 into buffer 0 (9 loads in flight)
  STAGE(0, 0, 0, 0);
  int gs = 0, rcs = 1;   // next chunk to stage

#pragma unroll 1
  for (int t = 0; t < 27; ++t) {
    const int aB = (t & 1) * 24576, bB = (t & 1) * 12288;
    if (t < 26) {
      STAGE(gs, rcs, aB ^ 24576, bB ^ 12288);   // issue next chunk FIRST
      if (++rcs == 3) { rcs = 0; ++gs; }
    }
    if (t > 0 && (t % 3) == 0) FOLD();          // group (t/3-1); hides under staging
    if (t < 26) { asm volatile("s_waitcnt vmcnt(9)" ::: "memory"); }
    else        { asm volatile("s_waitcnt vmcnt(0)" ::: "memory"); }
    __builtin_amdgcn_s_barrier();               // all threads' chunk-t loads landed
    asm volatile("" ::: "memory");
    __builtin_amdgcn_s_setprio(1);
#pragma unroll
    for (int ri = 0; ri < 3; ri++) {
      short8 afr[4], bfr[4];
#pragma unroll
      for (int mi = 0; mi < 4; mi++)
        afr[mi] = *(const short8*)&lA[aB + ri * 8192 + (wm + mi * 16 + fm) * RUN + swz * 8];
#pragma unroll
      for (int ni = 0; ni < 4; ni++)
        bfr[ni] = *(const short8*)&lB[bB + ri * 4096 + (wn + ni * 16 + fm) * RUN + swz * 8];
#pragma unroll
      for (int mi = 0; mi < 4; mi++)
#pragma unroll
        for (int ni = 0; ni < 4; ni++)
          acc[mi][ni] = __builtin_amdgcn_mfma_f32_16x16x32_bf16(afr[mi], bfr[ni], acc[mi][ni], 0, 0, 0);
    }
    __builtin_amdgcn_s_setprio(0);
    asm volatile("" ::: "memory");
    __builtin_amdgcn_s_barrier();               // all reads done before next overwrite
    asm volatile("" ::: "memory");
  }
  FOLD();                                       // group 8

  // ---- epilogue ----
#pragma unroll
  for (int mi = 0; mi < 4; mi++)
#pragma unroll
    for (int ni = 0; ni < 4; ni++) {
      int o = n0 + wn + ni * 16 + fm;
      int p = p0 + wm + mi * 16 + fq * 4;
      float4 o4;
      o4.x = tot[mi][ni][0] * 1e-3f;
      o4.y = tot[mi][ni][1] * 1e-3f;
      o4.z = tot[mi][ni][2] * 1e-3f;
      o4.w = tot[mi][ni][3] * 1e-3f;
      *(float4*)(out + ((size_t)(b * NO + o)) * NPIX + p) = o4;
    }
}

extern "C" void kernel_launch(void* const* d_in, const int* in_sizes, int n_in,
                              void* d_out, int out_size, void* d_ws, size_t ws_size,
                              hipStream_t stream) {
  const float* x = (const float*)d_in[0];
  const float* w = (const float*)d_in[1];
  float* out = (float*)d_out;

  float* pmax = (float*)d_ws;                                // 1088 slots
  u16* qa = (u16*)((char*)d_ws + 8192);                      // padded acts: 18,939,904 B
  u16* wq = (u16*)((char*)d_ws + 8192 + 18939904 + 8192);    // weights: 256*2592*2 B

  fused_pre<<<1376, 256, 0, stream>>>((const float4*)x, (NB * NC * NH * NW) / 4,
                                      (const float4*)w, (NO * NC * KPIX) / 4,
                                      pmax, qa);
  fused_quant<<<1024 + 2592, 256, 0, stream>>>(x, w, pmax, qa, wq, out + (out_size - 1));
  gemm_adc<<<dim3(128, 2), 512, 0, stream>>>(qa, wq, pmax, out);
}

// Round 2
// 154.838 us; speedup vs baseline: 1.0669x; 1.0669x over previous
//
#include <hip/hip_runtime.h>
#include <stdint.h>

typedef unsigned short u16;
typedef __attribute__((ext_vector_type(8))) short short8;
typedef __attribute__((ext_vector_type(4))) short s4v;
typedef __attribute__((ext_vector_type(4))) float floatx4;

#define NB 32
#define NC 256
#define NH 32
#define NW 32
#define NO 256
#define NPIX (NH*NW)     // 1024
#define KPIX 9
#define NG 9             // subarrays (groups)
#define RUN 32           // padded run length (per kernel-tap within group)
#define GK (NG*RUN)      // 288 k-slots per group
#define KTOT (NG*GK)     // 2592 k-slots
#define PADH 34
#define PADSP (PADH*PADH)       // 1156
#define QA_BSTRIDE (PADSP*NC)   // 295936 elems per batch
#define CHS 40                  // slab channel window (multiple of 8; covers delta<=4 + 32)

#define AS1 __attribute__((address_space(1)))
#define AS3 __attribute__((address_space(3)))

// ---------------- fused: per-block absmax slots + zero qa halo borders ----------------
// blocks [0,1024): x-max -> pmax[bid] ; [1024,1088): w-max ; [1088,1376): border zero
__global__ void fused_pre(const float4* __restrict__ x4, int nx4,
                          const float4* __restrict__ w4, int nw4,
                          float* __restrict__ pmax, u16* __restrict__ qa) {
  int bid = blockIdx.x;
  if (bid >= 1088) {
    int zb = bid - 1088;              // 9 blocks per batch
    int b = zb / 9;
    int rem = (zb % 9) * 256 + threadIdx.x;   // need <2112 (132 px * 16 ch-groups)
    if (rem >= 2112) return;
    int pb = rem >> 4, c16 = rem & 15;
    int y, x;
    if (pb < 68) { y = (pb >= 34) ? 33 : 0; x = pb % 34; }
    else { int q = pb - 68; y = 1 + (q >> 1); x = (q & 1) ? 33 : 0; }
    uint4 z; z.x = z.y = z.z = z.w = 0u;
    *(uint4*)(qa + ((size_t)(b * PADH + y) * PADH + x) * NC + c16 * 16) = z;
    return;
  }
  const float4* p; int n4; int nb, b0;
  if (bid < 1024) { p = x4; n4 = nx4; nb = 1024; b0 = bid; }
  else            { p = w4; n4 = nw4; nb = 64;   b0 = bid - 1024; }
  float m = 0.f;
  for (int i = b0 * blockDim.x + threadIdx.x; i < n4; i += nb * blockDim.x) {
    float4 v = p[i];
    m = fmaxf(m, fmaxf(fmaxf(fabsf(v.x), fabsf(v.y)), fmaxf(fabsf(v.z), fabsf(v.w))));
  }
#pragma unroll
  for (int off = 32; off > 0; off >>= 1)
    m = fmaxf(m, __shfl_down(m, off, 64));
  __shared__ float sm[4];
  int lane = threadIdx.x & 63, wv = threadIdx.x >> 6;
  if (lane == 0) sm[wv] = m;
  __syncthreads();
  if (threadIdx.x == 0)
    pmax[bid] = fmaxf(fmaxf(sm[0], sm[1]), fmaxf(sm[2], sm[3]));
}

// helper: reduce the 1024 x-slots and 64 w-slots
__device__ inline void reduce_pmax(const float* pmax, int tid, int nthreads,
                                   float* sred, float& mx_out, float& mw_out) {
  const float4* pf4 = (const float4*)pmax;
  float mx = 0.f, mw = 0.f;
  for (int t = tid; t < 256; t += nthreads) {
    float4 v = pf4[t];
    mx = fmaxf(mx, fmaxf(fmaxf(v.x, v.y), fmaxf(v.z, v.w)));
  }
  if (tid < 16) {
    float4 v = pf4[256 + tid];
    mw = fmaxf(fmaxf(v.x, v.y), fmaxf(v.z, v.w));
  }
#pragma unroll
  for (int off = 32; off > 0; off >>= 1) {
    mx = fmaxf(mx, __shfl_down(mx, off, 64));
    mw = fmaxf(mw, __shfl_down(mw, off, 64));
  }
  int lane = tid & 63, wv = tid >> 6, nw = nthreads >> 6;
  if (lane == 0) { sred[wv] = mx; sred[8 + wv] = mw; }
  __syncthreads();
  mx = sred[0]; mw = sred[8];
  for (int i = 1; i < nw; i++) { mx = fmaxf(mx, sred[i]); mw = fmaxf(mw, sred[8 + i]); }
  mx_out = mx; mw_out = mw;
}

// ---------------- fused quantization: acts (blocks <1024, vectorized) + weights ----------------
// act: one block per (b,y): 256c x 32x tile. float4 loads, LDS transpose, uint4 stores.
// f64 math EXACTLY as all passing rounds: rint((double)v * (255/s)).
__global__ void fused_quant(const float* __restrict__ x, const float* __restrict__ w,
                            const float* __restrict__ pmax,
                            u16* __restrict__ qa, u16* __restrict__ wq,
                            float* __restrict__ lossp) {
  __shared__ float sred[16];
  float mx, mw;
  reduce_pmax(pmax, threadIdx.x, 256, sred, mx, mw);
  int bid = blockIdx.x, tid = threadIdx.x;
  if (bid < 1024) {
    __shared__ u16 ts[32][264];        // [x][c], row stride 264 (16B-aligned rows)
    double s = (double)mx + 1e-12;
    double inv = 255.0 / s;
    int b = bid >> 5, y = bid & 31;
    const float4* x4 = (const float4*)x;
    int xc = tid & 7, crow = tid >> 3;
#pragma unroll
    for (int it = 0; it < 8; it++) {
      int c = crow + 32 * it;
      float4 v = x4[((size_t)(b * NC + c) * NH + y) * 8 + xc];
      float q0 = (float)rint((double)v.x * inv);
      float q1 = (float)rint((double)v.y * inv);
      float q2 = (float)rint((double)v.z * inv);
      float q3 = (float)rint((double)v.w * inv);
      ts[xc * 4 + 0][c] = (u16)(__float_as_uint(q0) >> 16);
      ts[xc * 4 + 1][c] = (u16)(__float_as_uint(q1) >> 16);
      ts[xc * 4 + 2][c] = (u16)(__float_as_uint(q2) >> 16);
      ts[xc * 4 + 3][c] = (u16)(__float_as_uint(q3) >> 16);
    }
    __syncthreads();
    int xx = tid >> 3, qwl = tid & 7;
    u16* orow = qa + ((size_t)(b * PADH + y + 1) * PADH + (xx + 1)) * NC;
#pragma unroll
    for (int it = 0; it < 4; it++) {
      int qw = qwl + 8 * it;
      *(uint4*)(orow + qw * 8) = *(const uint4*)&ts[xx][qw * 8];
    }
    return;
  }
  // ---- weights: 2592 blocks cover NO*KTOT = 663552 slots exactly ----
  double s = (double)mw + 1e-12;
  double inv = 15.0 / s;
  int idx = (bid - 1024) * 256 + tid;
  if (idx == 0) *lossp = 0.0f;                  // a_loss output
  int o = idx / KTOT, kk = idx % KTOT;
  int g = kk / GK, rem = kk % GK;
  int r = rem / RUN, j = rem % RUN;
  int clo = (256 * g - r + 8) / 9;
  int chi = (256 * (g + 1) - r + 8) / 9; if (chi > NC) chi = NC;
  int cst = clo & ~3;
  int c = cst + j;
  float val = 0.f;
  if (c >= clo && c < chi) {
    float wv = w[((size_t)o * NC + c) * KPIX + r];
    val = (float)rint((double)wv * inv);
  }
  wq[idx] = (u16)(__float_as_uint(val) >> 16);
}

// ---------------- fused GEMM + per-group ADC ----------------
// R0 frame (proven 75.8us): 128x128 tile, 256 threads (4 waves x 64x64), grid (256,2)
// = 512 blocks = 2/CU, drain-per-chunk barriers. NEW: A is staged as a per-group RAW
// qa SLAB (204 px x 40 ch = 16 KB, 4 async loads) instead of per-tap shifted copies
// (73.7 KB, 18 loads) -- the 9 taps read the slab directly at (py+rc)*34+(px+ri) with
// channel offset (cst-cw)+fq*8. Staged bytes/block 1.99MB -> 810KB (aggregate
// 680 -> 415 MB). Slab row stride = 40 u16 = 20 banks: b128 fragment reads are
// bank-uniform (8-cycle floor); delta=4 groups (g=7 r=0, g=8 r<=4) use b64 pairs
// (8B-aligned, ~2-way = free). Garbage channels past 256 hit zero-padded wq. B path,
// sync structure, f64 ADC fold, epilogue: byte-identical to the 75.8us kernel.
__global__ __launch_bounds__(256, 2) void gemm_adc(const u16* __restrict__ qa,
                                                   const u16* __restrict__ wq,
                                                   const float* __restrict__ pmax,
                                                   float* __restrict__ out) {
  __shared__ u16 sA[8192];            // 16 KB slab: 1024 slots x 16B (1020 used)
  __shared__ u16 lB[3 * 128 * RUN];   // 24 KB
  __shared__ float sred[16];
  const int tid = threadIdx.x;
  float mx, mw;
  reduce_pmax(pmax, tid, 256, sred, mx, mw);

  const int mblk = blockIdx.x, nblk = blockIdx.y;
  const int b = mblk >> 3;
  const int p0 = (mblk & 7) * 128;        // pixel base (4 image rows of 32)
  const int y0 = (mblk & 7) * 4;          // slab top row in padded coords
  const int n0 = nblk * 128;
  const int lane = tid & 63, wv = tid >> 6;
  const int wm = (wv & 1) * 64, wn = (wv >> 1) * 64;
  const int fm = lane & 15, fq = lane >> 4;
  const int swz = (fq + ((fm >> 1) & 3)) & 3;
  const int fq8 = fq * 8;

  double sa = (double)mx + 1e-12;
  double sw = (double)mw + 1e-12;
  double Sstep = sa * sw * 0.999 / 459.0;   // I/step = intsum * Sstep

  // per-thread slab pixel base (u16 units) for each mi fragment row
  int pix40[4];
#pragma unroll
  for (int mi = 0; mi < 4; mi++) {
    int pr = wm + mi * 16 + fm;
    pix40[mi] = ((pr >> 5) * 34 + (pr & 31)) * CHS;
  }

  // B staging: slot s = tid + 256*i (i=0..5): run = i>>1, row = (tid>>2) + 64*(i&1)
  // global k-word jsrc = ((tid&3) - ((tid>>3)&3)) & 3  (source-side bank swizzle)
  const int r0 = tid >> 2;
  const int jsrc = ((tid & 3) - ((tid >> 3) & 3)) & 3;
  const u16* BbH[2];
#pragma unroll
  for (int h = 0; h < 2; h++)
    BbH[h] = wq + (size_t)(n0 + r0 + 64 * h) * KTOT + jsrc * 8;

  // A slab source base: padded rows y0..y0+5, full 34 cols, channel window cw..cw+39
  const u16* Abase = qa + (size_t)b * QA_BSTRIDE + (size_t)y0 * PADH * NC;

  floatx4 acc[4][4];
  float tot[4][4][4];
#pragma unroll
  for (int mi = 0; mi < 4; mi++)
#pragma unroll
    for (int ni = 0; ni < 4; ni++)
#pragma unroll
      for (int rr = 0; rr < 4; rr++) { acc[mi][ni][rr] = 0.f; tot[mi][ni][rr] = 0.f; }

#pragma unroll 1
  for (int g = 0; g < NG; g++) {
    int cw = ((256 * g) / 9) & ~3;      // slab channel window start (= min cst over taps)
#pragma unroll 1
    for (int rc = 0; rc < 3; rc++) {
      int kb[3], dA[3];
#pragma unroll
      for (int ri = 0; ri < 3; ri++) {
        int r = rc * 3 + ri;
        int cst = ((256 * g - r + 8) / 9) & ~3;
        dA[ri] = cst - cw;              // in {0,4}
        kb[ri] = g * GK + r * RUN;
      }
      // A: slab for group g, staged once at rc==0 (prev slab's last read was before
      // the trailing barrier of the previous chunk). 4 async 16B loads/thread-slot.
      // slot s = py*170 + px*5 + j ; slots 1020..1023 stage safe garbage (never read).
      if (rc == 0) {
        const u16* src = Abase + cw;
#pragma unroll
        for (int i = 0; i < 4; i++) {
          int s = tid + 256 * i;
          int py = s / 170;
          int rem = s - py * 170;
          int px = rem / 5;
          int j = rem - px * 5;
          __builtin_amdgcn_global_load_lds(
              (const AS1 void*)(src + (py * PADH + px) * NC + j * 8),
              (AS3 void*)&sA[s * 8], 16, 0, 0);
        }
      }
      // B: 6 async 16B loads (3 runs x 2 row-halves of 64)
#pragma unroll
      for (int i = 0; i < 6; i++)
        __builtin_amdgcn_global_load_lds(
            (const AS1 void*)(BbH[i & 1] + kb[i >> 1]),
            (AS3 void*)&lB[(tid + 256 * i) * 8], 16, 0, 0);
      __syncthreads();
      // ---- 3 runs x 16 MFMA per wave ----
#pragma unroll
      for (int ri = 0; ri < 3; ri++) {
        short8 afr[4], bfr[4];
        int po = rc * (34 * CHS) + ri * CHS + dA[ri] + fq8;
        if (dA[ri] == 0) {              // 16B-aligned: single ds_read_b128, bank-uniform
#pragma unroll
          for (int mi = 0; mi < 4; mi++)
            afr[mi] = *(const short8*)&sA[pix40[mi] + po];
        } else {                        // 8B-aligned: two ds_read_b64
#pragma unroll
          for (int mi = 0; mi < 4; mi++) {
            union { short8 v8; s4v v4[2]; } u;
            u.v4[0] = *(const s4v*)&sA[pix40[mi] + po];
            u.v4[1] = *(const s4v*)&sA[pix40[mi] + po + 4];
            afr[mi] = u.v8;
          }
        }
#pragma unroll
        for (int ni = 0; ni < 4; ni++)
          bfr[ni] = *(const short8*)&lB[ri * 4096 + (wn + ni * 16 + fm) * RUN + swz * 8];
#pragma unroll
        for (int mi = 0; mi < 4; mi++)
#pragma unroll
          for (int ni = 0; ni < 4; ni++)
            acc[mi][ni] = __builtin_amdgcn_mfma_f32_16x16x32_bf16(afr[mi], bfr[ni], acc[mi][ni], 0, 0, 0);
      }
      __syncthreads();
    }
    // ---- per-group ADC fold (f64 mul+rint EXACTLY as the passing kernels) ----
#pragma unroll
    for (int mi = 0; mi < 4; mi++)
#pragma unroll
      for (int ni = 0; ni < 4; ni++)
#pragma unroll
        for (int rr = 0; rr < 4; rr++) {
          double d = (double)acc[mi][ni][rr] * Sstep;
          float tf = (float)rint(d);
          tf = fminf(fmaxf(tf, -128.f), 127.f);
          tot[mi][ni][rr] += tf;
          acc[mi][ni][rr] = 0.f;
        }
  }
  // ---- epilogue ----
#pragma unroll
  for (int mi = 0; mi < 4; mi++)
#pragma unroll
    for (int ni = 0; ni < 4; ni++) {
      int o = n0 + wn + ni * 16 + fm;
      int p = p0 + wm + mi * 16 + fq * 4;
      float4 o4;
      o4.x = tot[mi][ni][0] * 1e-3f;
      o4.y = tot[mi][ni][1] * 1e-3f;
      o4.z = tot[mi][ni][2] * 1e-3f;
      o4.w = tot[mi][ni][3] * 1e-3f;
      *(float4*)(out + ((size_t)(b * NO + o)) * NPIX + p) = o4;
    }
}

extern "C" void kernel_launch(void* const* d_in, const int* in_sizes, int n_in,
                              void* d_out, int out_size, void* d_ws, size_t ws_size,
                              hipStream_t stream) {
  const float* x = (const float*)d_in[0];
  const float* w = (const float*)d_in[1];
  float* out = (float*)d_out;

  float* pmax = (float*)d_ws;                                // 1088 slots
  u16* qa = (u16*)((char*)d_ws + 8192);                      // padded acts: 18,939,904 B
  u16* wq = (u16*)((char*)d_ws + 8192 + 18939904 + 8192);    // weights: 256*2592*2 B

  fused_pre<<<1376, 256, 0, stream>>>((const float4*)x, (NB * NC * NH * NW) / 4,
                                      (const float4*)w, (NO * NC * KPIX) / 4,
                                      pmax, qa);
  fused_quant<<<1024 + 2592, 256, 0, stream>>>(x, w, pmax, qa, wq, out + (out_size - 1));
  gemm_adc<<<dim3(256, 2), 256, 0, stream>>>(qa, wq, pmax, out);
}